// Round 10
// baseline (90.322 us; speedup 1.0000x reference)
//
#include <hip/hip_runtime.h>
#include <hip/hip_fp16.h>
#include <math.h>

#define NDET 512
#define NANG 180
#define NB   8
#define NIMG 512

// ---- ws layout in floats ----
#define WS_CASA 0                      // 180 x {ca,sa} = 360 floats
#define WS_CBT  360                    // cbt[tile][angle] = 256*180 floats
#define WS_FGH  46464                  // fgh[a][d][b] halves: 180*512*8*2B = 368,640 floats
#define WS_BP   (46464 + 368640)       // bp image [8][512][512] fp32

typedef _Float16 h2_t __attribute__((ext_vector_type(2)));

__device__ __forceinline__ void gld_lds16(const void* g, void* l) {
    __builtin_amdgcn_global_load_lds((__attribute__((address_space(1))) void*)g,
                                     (__attribute__((address_space(3))) void*)l,
                                     16, 0, 0);
}

__device__ __forceinline__ int hswz(int s) {            // swizzled h-chunk slot
    return (s & 0x78) | ((s ^ (s >> 3)) & 7);
}

// ---------------- kernel 1: Ram-Lak filter (h inline) + tables + fp16 store ----------------
__global__ __launch_bounds__(256) void k_filter(const float* __restrict__ x, float* ws) {
    __shared__ float xs[8 * 516];      // 8 padded sinogram rows
    __shared__ float hrs[512];         // swizzled h chunks
    const int a     = blockIdx.x >> 1;
    const int half_ = blockIdx.x & 1;
    const int tid   = threadIdx.x;
    const int lane  = tid & 63;
    const int wv    = tid >> 6;        // 0..3

    // compute h inline (closed form) into swizzled LDS
    #pragma unroll
    for (int p = 0; p < 2; ++p) {
        int n = tid + 256 * p;
        float h;
        if (n == 0) h = 0.25f;
        else if ((n & 1) == 0) h = 0.0f;
        else {
            double th = (double)n * (M_PI / 256.0);
            double s2 = sin(0.5 * th);
            double S  = (254.0 - 256.0 * cos(th)) / (4.0 * s2 * s2);
            h = (float)((2.0 * S - 256.0) / 262144.0);
        }
        hrs[hswz(n >> 2) * 4 + (n & 3)] = h;
    }
    // stage 8 sinogram rows for angle a
    {
        int b  = wv * 2 + (lane >> 5);
        int l5 = lane & 31;
        const float* xr = x + (b * NANG + a) * NDET;
        float* xd = xs + b * 516;
        #pragma unroll
        for (int p = 0; p < 4; ++p) {
            int idx = l5 * 4 + p * 128;
            *(float4*)(xd + idx) = *(const float4*)(xr + idx);
        }
    }
    // angle tables + per-(tile,angle) window base (only half_==0 blocks)
    if (half_ == 0) {
        double th = (double)a * (M_PI / 180.0);
        double sc = 255.5 / sqrt(2.0);
        const float ca = (float)(cos(th) * sc), sa = (float)(sin(th) * sc);
        if (tid == 0) {
            ws[WS_CASA + 2 * a]     = ca;
            ws[WS_CASA + 2 * a + 1] = sa;
        }
        const int bx = tid & 15, by = tid >> 4;        // tid = tile id (32x32 tiles)
        const float x0 = -1.f + (float)(bx * 32)      * (2.f / 511.f);
        const float x1 = -1.f + (float)(bx * 32 + 31) * (2.f / 511.f);
        const float y0 = -1.f + (float)(by * 32)      * (2.f / 511.f);
        const float y1 = -1.f + (float)(by * 32 + 31) * (2.f / 511.f);
        float u00 = fmaf(x0, ca, fmaf(y0, sa, 255.5f));
        float u01 = fmaf(x1, ca, fmaf(y0, sa, 255.5f));
        float u10 = fmaf(x0, ca, fmaf(y1, sa, 255.5f));
        float u11 = fmaf(x1, ca, fmaf(y1, sa, 255.5f));
        float umin = fminf(fminf(u00, u01), fminf(u10, u11));
        int d0 = (int)floorf(umin);                    // no -1 slack; 34-slot window
        d0 = max(0, min(NDET - 34, d0));
        ws[WS_CBT + tid * 180 + a] = 255.5f - (float)d0;
    }
    __syncthreads();

    const int b  = lane & 7;
    const int t  = lane >> 3;
    const int n0 = half_ * 256 + wv * 64 + t * 8;
    const int q  = n0 >> 2;
    const float* xrow = xs + b * 516;

    float acc[8] = {0, 0, 0, 0, 0, 0, 0, 0};
    float win[12];
    {
        int s2 = (-q - 2) & 127;
        int s1 = (-q - 1) & 127;
        float4 h2 = *(const float4*)(hrs + hswz(s2) * 4);
        float4 h1 = *(const float4*)(hrs + hswz(s1) * 4);
        win[0] = h2.x; win[1] = h2.y; win[2]  = h2.z; win[3]  = h2.w;
        win[4] = h1.x; win[5] = h1.y; win[6]  = h1.z; win[7]  = h1.w;
    }
    #pragma unroll 2
    for (int c = 0; c < 128; ++c) {
        int s = (c - q) & 127;
        float4 hc = *(const float4*)(hrs + hswz(s) * 4);
        win[8] = hc.x; win[9] = hc.y; win[10] = hc.z; win[11] = hc.w;
        float4 xv = *(const float4*)(xrow + c * 4);
        float xa[4] = {xv.x, xv.y, xv.z, xv.w};
        #pragma unroll
        for (int k = 0; k < 8; ++k)
            #pragma unroll
            for (int j = 0; j < 4; ++j)
                acc[k] = fmaf(xa[j], win[8 + j - k], acc[k]);
        #pragma unroll
        for (int i2 = 0; i2 < 8; ++i2) win[i2] = win[i2 + 4];
    }
    __half* fgh = (__half*)(ws + WS_FGH);
    #pragma unroll
    for (int k = 0; k < 8; ++k)
        fgh[(a * NDET + n0 + k) * NB + b] = __float2half(acc[k]);
}

// ---------------- kernel 2: backprojection (angle-halved blocks, 2 blocks/CU) ----------------
// grid 512: bid = tile + 256*half. Each block: 32x32 px tile, 90 angles,
// window 34 dets x 8 batches fp16 = 48.96 KB LDS. Results combined via atomicAdd
// (exactly 2 commuting contributors per address -> bitwise deterministic).
#define WWIN 34
#define CHANG 90
#define NCHK (CHANG * WWIN)            // 3060 16B chunks

__global__ __launch_bounds__(1024, 8) void k_bp(float* ws) {
    __shared__ uint4 win4[NCHK];       // 48,960 B
    const int tid  = threadIdx.x;
    const int wv   = tid >> 6, lane = tid & 63;
    const int tile = blockIdx.x & 255;
    const int ah   = (blockIdx.x >> 8) * CHANG;        // 0 or 90
    const int bx   = tile & 15, by = tile >> 4;
    const int iy   = by * 32 + (wv >> 2) * 8 + (lane >> 3);
    const int ix   = bx * 32 + (wv & 3) * 8 + (lane & 7);
    const float xf = -1.0f + (float)ix * (2.0f / 511.0f);
    const float yf = -1.0f + (float)iy * (2.0f / 511.0f);

    const __half* __restrict__ fgh  = (const __half*)(ws + WS_FGH);
    const float*  __restrict__ cbt  = ws + WS_CBT + tile * 180;  // this tile's column
    const float*  __restrict__ casa = ws + WS_CASA;

    // stage 90 windows: chunk c -> local angle a=c/34, det d0+o, o=c%34
    #pragma unroll
    for (int r = 0; r < 3; ++r) {
        int c = r * 1024 + tid;
        if (c < NCHK) {
            unsigned a = (unsigned)c / 34u;
            int o  = c - (int)a * 34;
            int ag = ah + (int)a;
            float cb = cbt[ag];
            int d0 = (int)(255.5f - cb);
            gld_lds16(fgh + (ag * NDET + d0 + o) * NB, win4 + c);
        }
    }
    __syncthreads();

    float acc[8] = {0, 0, 0, 0, 0, 0, 0, 0};
    #pragma unroll 4
    for (int al = 0; al < CHANG; ++al) {
        const int ag = ah + al;
        const float2 cs = *(const float2*)(casa + 2 * ag);   // uniform -> s_load
        const float  cb = cbt[ag];                           // uniform -> s_load
        float v = fmaf(xf, cs.x, fmaf(yf, cs.y, cb));
        v = __builtin_amdgcn_fmed3f(v, 0.0f, 32.99996948f);
        float fj = floorf(v);
        float w  = v - fj;
        int  j0  = (int)fj;
        const char* pc = (const char*)win4 + al * (WWIN * 16) + (j0 << 4);
        uint4 da = *(const uint4*)pc;            // det j0:   batches 0..7 (4x half2)
        uint4 db = *(const uint4*)(pc + 16);     // det j0+1: batches 0..7
        h2_t wp = __builtin_bit_cast(h2_t, __builtin_amdgcn_cvt_pkrtz(1.0f - w, w)); // (1-w, w)
        unsigned pl0 = __builtin_amdgcn_perm(db.x, da.x, 0x05040100u); // (A lo, B lo)
        unsigned ph0 = __builtin_amdgcn_perm(db.x, da.x, 0x07060302u); // (A hi, B hi)
        unsigned pl1 = __builtin_amdgcn_perm(db.y, da.y, 0x05040100u);
        unsigned ph1 = __builtin_amdgcn_perm(db.y, da.y, 0x07060302u);
        unsigned pl2 = __builtin_amdgcn_perm(db.z, da.z, 0x05040100u);
        unsigned ph2 = __builtin_amdgcn_perm(db.z, da.z, 0x07060302u);
        unsigned pl3 = __builtin_amdgcn_perm(db.w, da.w, 0x05040100u);
        unsigned ph3 = __builtin_amdgcn_perm(db.w, da.w, 0x07060302u);
        acc[0] = __builtin_amdgcn_fdot2(__builtin_bit_cast(h2_t, pl0), wp, acc[0], false);
        acc[1] = __builtin_amdgcn_fdot2(__builtin_bit_cast(h2_t, ph0), wp, acc[1], false);
        acc[2] = __builtin_amdgcn_fdot2(__builtin_bit_cast(h2_t, pl1), wp, acc[2], false);
        acc[3] = __builtin_amdgcn_fdot2(__builtin_bit_cast(h2_t, ph1), wp, acc[3], false);
        acc[4] = __builtin_amdgcn_fdot2(__builtin_bit_cast(h2_t, pl2), wp, acc[4], false);
        acc[5] = __builtin_amdgcn_fdot2(__builtin_bit_cast(h2_t, ph2), wp, acc[5], false);
        acc[6] = __builtin_amdgcn_fdot2(__builtin_bit_cast(h2_t, pl3), wp, acc[6], false);
        acc[7] = __builtin_amdgcn_fdot2(__builtin_bit_cast(h2_t, ph3), wp, acc[7], false);
    }

    const float scale = (float)((2.0 / 512.0) * M_PI / 180.0);
    float* bp = ws + WS_BP;
    #pragma unroll
    for (int b = 0; b < 8; ++b)
        atomicAdd(&bp[b * (NIMG * NIMG) + iy * NIMG + ix], acc[b] * scale);
}

// ---------------- kernel 3: 3x3 gaussian blur + clip ----------------
__global__ __launch_bounds__(256) void k_blur(const float* __restrict__ ws, float* __restrict__ out) {
    const int gid = blockIdx.x * 256 + threadIdx.x;
    const int b  = gid >> 18;
    const int r  = (gid >> 9) & 511;
    const int cx = gid & 511;
    const float KA = 0.10650697891920077f;   // e^-2 / (1+2e^-2)
    const float KB = 0.78698604216159850f;   // 1 / (1+2e^-2)
    const float* img = ws + WS_BP + b * (NIMG * NIMG);
    const float* rp = img + r * 512 + cx;

    float rowm = 0.0f, row0, rowp = 0.0f;
    {
        float l  = (cx > 0)   ? rp[-1] : 0.0f;
        float rr = (cx < 511) ? rp[1]  : 0.0f;
        row0 = KA * (l + rr) + KB * rp[0];
    }
    if (r > 0) {
        const float* q = rp - 512;
        float l  = (cx > 0)   ? q[-1] : 0.0f;
        float rr = (cx < 511) ? q[1]  : 0.0f;
        rowm = KA * (l + rr) + KB * q[0];
    }
    if (r < 511) {
        const float* q = rp + 512;
        float l  = (cx > 0)   ? q[-1] : 0.0f;
        float rr = (cx < 511) ? q[1]  : 0.0f;
        rowp = KA * (l + rr) + KB * q[0];
    }
    float v = KA * (rowm + rowp) + KB * row0;
    v = fminf(fmaxf(v, -1.0f), 1.0f);
    out[gid] = v;
}

extern "C" void kernel_launch(void* const* d_in, const int* in_sizes, int n_in,
                              void* d_out, int out_size, void* d_ws, size_t ws_size,
                              hipStream_t stream) {
    const float* x = (const float*)d_in[0];
    float* out = (float*)d_out;
    float* ws  = (float*)d_ws;

    k_filter<<<NANG * 2, 256, 0, stream>>>(x, ws);
    hipMemsetAsync(ws + WS_BP, 0, (size_t)NB * NIMG * NIMG * sizeof(float), stream);
    k_bp<<<512, 1024, 0, stream>>>(ws);
    k_blur<<<(NB * NIMG * NIMG) / 256, 256, 0, stream>>>(ws, out);
}

// Round 11
// 69.162 us; speedup vs baseline: 1.3059x; 1.3059x over previous
//
#include <hip/hip_runtime.h>
#include <hip/hip_fp16.h>
#include <math.h>

#define NDET 512
#define NANG 180
#define NB   8
#define NIMG 512

// ---- ws layout in floats ----
#define WS_CASA 0                      // 180 x {ca,sa} = 360 floats
#define WS_CBT  360                    // cbt[tile][angle] = 256*180 floats
#define WS_FGH  46464                  // fgh[a][d][b] halves: 180*512*8*2B = 368,640 floats
#define WS_BP   (46464 + 368640)       // bp image [8][512][512] fp32

typedef _Float16 h2_t __attribute__((ext_vector_type(2)));

__device__ __forceinline__ int hswz(int s) {            // swizzled h-chunk slot
    return (s & 0x78) | ((s ^ (s >> 3)) & 7);
}

// ---------------- kernel 1: Ram-Lak filter (h inline) + tables + fp16 store ----------------
__global__ __launch_bounds__(256) void k_filter(const float* __restrict__ x, float* ws) {
    __shared__ float xs[8 * 516];      // 8 padded sinogram rows
    __shared__ float hrs[512];         // swizzled h chunks
    const int a     = blockIdx.x >> 1;
    const int half_ = blockIdx.x & 1;
    const int tid   = threadIdx.x;
    const int lane  = tid & 63;
    const int wv    = tid >> 6;        // 0..3

    // compute h inline (closed form) into swizzled LDS
    #pragma unroll
    for (int p = 0; p < 2; ++p) {
        int n = tid + 256 * p;
        float h;
        if (n == 0) h = 0.25f;
        else if ((n & 1) == 0) h = 0.0f;
        else {
            double th = (double)n * (M_PI / 256.0);
            double s2 = sin(0.5 * th);
            double S  = (254.0 - 256.0 * cos(th)) / (4.0 * s2 * s2);
            h = (float)((2.0 * S - 256.0) / 262144.0);
        }
        hrs[hswz(n >> 2) * 4 + (n & 3)] = h;
    }
    // stage 8 sinogram rows for angle a
    {
        int b  = wv * 2 + (lane >> 5);
        int l5 = lane & 31;
        const float* xr = x + (b * NANG + a) * NDET;
        float* xd = xs + b * 516;
        #pragma unroll
        for (int p = 0; p < 4; ++p) {
            int idx = l5 * 4 + p * 128;
            *(float4*)(xd + idx) = *(const float4*)(xr + idx);
        }
    }
    // angle tables + per-(tile,angle) window base (only half_==0 blocks)
    if (half_ == 0) {
        double th = (double)a * (M_PI / 180.0);
        double sc = 255.5 / sqrt(2.0);
        const float ca = (float)(cos(th) * sc), sa = (float)(sin(th) * sc);
        if (tid == 0) {
            ws[WS_CASA + 2 * a]     = ca;
            ws[WS_CASA + 2 * a + 1] = sa;
        }
        const int bx = tid & 15, by = tid >> 4;        // tid = tile id (32x32 tiles)
        const float x0 = -1.f + (float)(bx * 32)      * (2.f / 511.f);
        const float x1 = -1.f + (float)(bx * 32 + 31) * (2.f / 511.f);
        const float y0 = -1.f + (float)(by * 32)      * (2.f / 511.f);
        const float y1 = -1.f + (float)(by * 32 + 31) * (2.f / 511.f);
        float u00 = fmaf(x0, ca, fmaf(y0, sa, 255.5f));
        float u01 = fmaf(x1, ca, fmaf(y0, sa, 255.5f));
        float u10 = fmaf(x0, ca, fmaf(y1, sa, 255.5f));
        float u11 = fmaf(x1, ca, fmaf(y1, sa, 255.5f));
        float umin = fminf(fminf(u00, u01), fminf(u10, u11));
        int d0 = (int)floorf(umin);                    // 33-entry window
        d0 = max(0, min(NDET - 34, d0));
        ws[WS_CBT + tid * 180 + a] = 255.5f - (float)d0;
    }
    __syncthreads();

    const int b  = lane & 7;
    const int t  = lane >> 3;
    const int n0 = half_ * 256 + wv * 64 + t * 8;
    const int q  = n0 >> 2;
    const float* xrow = xs + b * 516;

    float acc[8] = {0, 0, 0, 0, 0, 0, 0, 0};
    float win[12];
    {
        int s2 = (-q - 2) & 127;
        int s1 = (-q - 1) & 127;
        float4 h2 = *(const float4*)(hrs + hswz(s2) * 4);
        float4 h1 = *(const float4*)(hrs + hswz(s1) * 4);
        win[0] = h2.x; win[1] = h2.y; win[2]  = h2.z; win[3]  = h2.w;
        win[4] = h1.x; win[5] = h1.y; win[6]  = h1.z; win[7]  = h1.w;
    }
    #pragma unroll 2
    for (int c = 0; c < 128; ++c) {
        int s = (c - q) & 127;
        float4 hc = *(const float4*)(hrs + hswz(s) * 4);
        win[8] = hc.x; win[9] = hc.y; win[10] = hc.z; win[11] = hc.w;
        float4 xv = *(const float4*)(xrow + c * 4);
        float xa[4] = {xv.x, xv.y, xv.z, xv.w};
        #pragma unroll
        for (int k = 0; k < 8; ++k)
            #pragma unroll
            for (int j = 0; j < 4; ++j)
                acc[k] = fmaf(xa[j], win[8 + j - k], acc[k]);
        #pragma unroll
        for (int i2 = 0; i2 < 8; ++i2) win[i2] = win[i2 + 4];
    }
    __half* fgh = (__half*)(ws + WS_FGH);
    #pragma unroll
    for (int k = 0; k < 8; ++k)
        fgh[(a * NDET + n0 + k) * NB + b] = __float2half(acc[k]);
}

// ---------------- kernel 2: backprojection (pre-paired LDS, 3 chunks dbuf) ----------------
// Block = 32x32 px tile, 1024 thr. 3 chunks of 60 angles; per angle 33 paired
// entries: regionA[j]=(f[j].b0,f[j+1].b0,..,b3) 16B, regionB = b4..b7.
// Pairing perms done ONCE at staging (reg-staged), not per (pixel,angle).
#define WWE  33
#define CHA  60
#define ECH  (CHA * WWE)               // 1980 entries per chunk per region

#define PERM_LO 0x05040100u
#define PERM_HI 0x07060302u

__global__ __launch_bounds__(1024, 4) void k_bp(float* ws) {
    __shared__ uint4 win4[2][2 * ECH];   // 126,720 B
    const int tid  = threadIdx.x;
    const int wv   = tid >> 6, lane = tid & 63;
    const int tile = blockIdx.x;
    const int bx   = tile & 15, by = tile >> 4;
    const int iy   = by * 32 + (wv >> 2) * 8 + (lane >> 3);
    const int ix   = bx * 32 + (wv & 3) * 8 + (lane & 7);
    const float xf = -1.0f + (float)ix * (2.0f / 511.0f);
    const float yf = -1.0f + (float)iy * (2.0f / 511.0f);

    const __half* __restrict__ fgh  = (const __half*)(ws + WS_FGH);
    const float*  __restrict__ cbt  = ws + WS_CBT + tile * 180;
    const float*  __restrict__ casa = ws + WS_CASA;

    const int e0 = tid, e1 = tid + 1024;        // e0 < 1980 always; e1 maybe
    uint4 sA0, sB0, sA1, sB1;                   // staged rows (det d, det d+1)

    auto sload = [&](int ch) {
        {
            int a = e0 / 33, j = e0 - a * 33, ag = ch * CHA + a;
            int d0 = (int)(255.5f - cbt[ag]);
            const uint4* s = (const uint4*)(fgh + (ag * NDET + d0 + j) * NB);
            sA0 = s[0]; sB0 = s[1];
        }
        if (e1 < ECH) {
            int a = e1 / 33, j = e1 - a * 33, ag = ch * CHA + a;
            int d0 = (int)(255.5f - cbt[ag]);
            const uint4* s = (const uint4*)(fgh + (ag * NDET + d0 + j) * NB);
            sA1 = s[0]; sB1 = s[1];
        }
    };
    auto swrite = [&](int buf) {
        uint4 ra, rb;
        ra.x = __builtin_amdgcn_perm(sB0.x, sA0.x, PERM_LO);
        ra.y = __builtin_amdgcn_perm(sB0.x, sA0.x, PERM_HI);
        ra.z = __builtin_amdgcn_perm(sB0.y, sA0.y, PERM_LO);
        ra.w = __builtin_amdgcn_perm(sB0.y, sA0.y, PERM_HI);
        rb.x = __builtin_amdgcn_perm(sB0.z, sA0.z, PERM_LO);
        rb.y = __builtin_amdgcn_perm(sB0.z, sA0.z, PERM_HI);
        rb.z = __builtin_amdgcn_perm(sB0.w, sA0.w, PERM_LO);
        rb.w = __builtin_amdgcn_perm(sB0.w, sA0.w, PERM_HI);
        win4[buf][e0] = ra; win4[buf][ECH + e0] = rb;
        if (e1 < ECH) {
            uint4 rc, rd;
            rc.x = __builtin_amdgcn_perm(sB1.x, sA1.x, PERM_LO);
            rc.y = __builtin_amdgcn_perm(sB1.x, sA1.x, PERM_HI);
            rc.z = __builtin_amdgcn_perm(sB1.y, sA1.y, PERM_LO);
            rc.w = __builtin_amdgcn_perm(sB1.y, sA1.y, PERM_HI);
            rd.x = __builtin_amdgcn_perm(sB1.z, sA1.z, PERM_LO);
            rd.y = __builtin_amdgcn_perm(sB1.z, sA1.z, PERM_HI);
            rd.z = __builtin_amdgcn_perm(sB1.w, sA1.w, PERM_LO);
            rd.w = __builtin_amdgcn_perm(sB1.w, sA1.w, PERM_HI);
            win4[buf][e1] = rc; win4[buf][ECH + e1] = rd;
        }
    };

    float acc[8] = {0, 0, 0, 0, 0, 0, 0, 0};
    auto comp = [&](int buf, int ch) {
        const uint4* base = &win4[buf][0];
        #pragma unroll 4
        for (int al = 0; al < CHA; ++al) {
            const int ag = ch * CHA + al;
            const float2 cs = *(const float2*)(casa + 2 * ag);   // uniform
            const float  cb = cbt[ag];                           // uniform
            float v = fmaf(xf, cs.x, fmaf(yf, cs.y, cb));
            v = __builtin_amdgcn_fmed3f(v, 0.0f, 32.99996948f);
            float fj = floorf(v);
            float w  = v - fj;
            int  j0  = (int)fj;
            const uint4* p = base + al * WWE + j0;
            uint4 dA = p[0];          // (A,B) pairs batches 0..3
            uint4 dB = p[ECH];        // (A,B) pairs batches 4..7
            h2_t wp = __builtin_bit_cast(h2_t, __builtin_amdgcn_cvt_pkrtz(1.0f - w, w));
            acc[0] = __builtin_amdgcn_fdot2(__builtin_bit_cast(h2_t, dA.x), wp, acc[0], false);
            acc[1] = __builtin_amdgcn_fdot2(__builtin_bit_cast(h2_t, dA.y), wp, acc[1], false);
            acc[2] = __builtin_amdgcn_fdot2(__builtin_bit_cast(h2_t, dA.z), wp, acc[2], false);
            acc[3] = __builtin_amdgcn_fdot2(__builtin_bit_cast(h2_t, dA.w), wp, acc[3], false);
            acc[4] = __builtin_amdgcn_fdot2(__builtin_bit_cast(h2_t, dB.x), wp, acc[4], false);
            acc[5] = __builtin_amdgcn_fdot2(__builtin_bit_cast(h2_t, dB.y), wp, acc[5], false);
            acc[6] = __builtin_amdgcn_fdot2(__builtin_bit_cast(h2_t, dB.z), wp, acc[6], false);
            acc[7] = __builtin_amdgcn_fdot2(__builtin_bit_cast(h2_t, dB.w), wp, acc[7], false);
        }
    };

    // chunk pipeline: ch0->buf0, ch1->buf1, ch2->buf0 (T14 async-stage)
    sload(0); swrite(0); __syncthreads();
    sload(1); comp(0, 0); swrite(1); __syncthreads();
    sload(2); comp(1, 1); swrite(0); __syncthreads();
    comp(0, 2);

    const float scale = (float)((2.0 / 512.0) * M_PI / 180.0);
    float* bp = ws + WS_BP;
    #pragma unroll
    for (int b = 0; b < 8; ++b)
        bp[b * (NIMG * NIMG) + iy * NIMG + ix] = acc[b] * scale;
}

// ---------------- kernel 3: 3x3 gaussian blur + clip ----------------
__global__ __launch_bounds__(256) void k_blur(const float* __restrict__ ws, float* __restrict__ out) {
    const int gid = blockIdx.x * 256 + threadIdx.x;
    const int b  = gid >> 18;
    const int r  = (gid >> 9) & 511;
    const int cx = gid & 511;
    const float KA = 0.10650697891920077f;   // e^-2 / (1+2e^-2)
    const float KB = 0.78698604216159850f;   // 1 / (1+2e^-2)
    const float* img = ws + WS_BP + b * (NIMG * NIMG);
    const float* rp = img + r * 512 + cx;

    float rowm = 0.0f, row0, rowp = 0.0f;
    {
        float l  = (cx > 0)   ? rp[-1] : 0.0f;
        float rr = (cx < 511) ? rp[1]  : 0.0f;
        row0 = KA * (l + rr) + KB * rp[0];
    }
    if (r > 0) {
        const float* q = rp - 512;
        float l  = (cx > 0)   ? q[-1] : 0.0f;
        float rr = (cx < 511) ? q[1]  : 0.0f;
        rowm = KA * (l + rr) + KB * q[0];
    }
    if (r < 511) {
        const float* q = rp + 512;
        float l  = (cx > 0)   ? q[-1] : 0.0f;
        float rr = (cx < 511) ? q[1]  : 0.0f;
        rowp = KA * (l + rr) + KB * q[0];
    }
    float v = KA * (rowm + rowp) + KB * row0;
    v = fminf(fmaxf(v, -1.0f), 1.0f);
    out[gid] = v;
}

extern "C" void kernel_launch(void* const* d_in, const int* in_sizes, int n_in,
                              void* d_out, int out_size, void* d_ws, size_t ws_size,
                              hipStream_t stream) {
    const float* x = (const float*)d_in[0];
    float* out = (float*)d_out;
    float* ws  = (float*)d_ws;

    k_filter<<<NANG * 2, 256, 0, stream>>>(x, ws);
    k_bp<<<256, 1024, 0, stream>>>(ws);
    k_blur<<<(NB * NIMG * NIMG) / 256, 256, 0, stream>>>(ws, out);
}

// Round 12
// 68.612 us; speedup vs baseline: 1.3164x; 1.0080x over previous
//
#include <hip/hip_runtime.h>
#include <hip/hip_fp16.h>
#include <math.h>

#define NDET 512
#define NANG 180
#define NB   8
#define NIMG 512

// ---- ws layout in floats ----
#define WS_CASA 0                      // 180 x {ca,sa} = 360 floats
#define WS_CBT  360                    // cbt[tile][angle] = 256*180 floats
#define WS_FGH  46464                  // fgh[a][d][b] halves: 180*512*8*2B = 368,640 floats
#define WS_BP   (46464 + 368640)       // bp image [8][512][512] fp32

typedef _Float16 h2_t __attribute__((ext_vector_type(2)));

__device__ __forceinline__ int hswz(int s) {            // swizzled h-chunk slot
    return (s & 0x78) | ((s ^ (s >> 3)) & 7);
}

// ---------------- kernel 1: Ram-Lak filter (h inline) + tables + fp16 store ----------------
// h[n] closed form (simplified): h[0]=0.25, even n -> 0, odd n ->
//   h[n] = -1/(262144 * sin^2(pi*n/512))   [= -2/((1-cos)*512^2), verified vs irfft]
__global__ __launch_bounds__(256) void k_filter(const float* __restrict__ x, float* ws) {
    __shared__ float xs[8 * 516];      // 8 padded sinogram rows
    __shared__ float hrs[512];         // swizzled h chunks
    const int a     = blockIdx.x >> 1;
    const int half_ = blockIdx.x & 1;
    const int tid   = threadIdx.x;
    const int lane  = tid & 63;
    const int wv    = tid >> 6;        // 0..3

    // compute h inline (fp32 closed form) into swizzled LDS
    #pragma unroll
    for (int p = 0; p < 2; ++p) {
        int n = tid + 256 * p;
        float h;
        if (n == 0) h = 0.25f;
        else if ((n & 1) == 0) h = 0.0f;
        else {
            int m = min(n, 512 - n);                   // symmetric; arg <= pi/2
            float s = __sinf((float)m * (float)(M_PI / 512.0));
            h = -1.0f / (262144.0f * s * s);
        }
        hrs[hswz(n >> 2) * 4 + (n & 3)] = h;
    }
    // stage 8 sinogram rows for angle a
    {
        int b  = wv * 2 + (lane >> 5);
        int l5 = lane & 31;
        const float* xr = x + (b * NANG + a) * NDET;
        float* xd = xs + b * 516;
        #pragma unroll
        for (int p = 0; p < 4; ++p) {
            int idx = l5 * 4 + p * 128;
            *(float4*)(xd + idx) = *(const float4*)(xr + idx);
        }
    }
    // angle tables + per-(tile,angle) window base (only half_==0 blocks)
    if (half_ == 0) {
        double th = (double)a * (M_PI / 180.0);
        double sc = 255.5 / sqrt(2.0);
        const float ca = (float)(cos(th) * sc), sa = (float)(sin(th) * sc);
        if (tid == 0) {
            ws[WS_CASA + 2 * a]     = ca;
            ws[WS_CASA + 2 * a + 1] = sa;
        }
        const int bx = tid & 15, by = tid >> 4;        // tid = tile id (32x32 tiles)
        const float x0 = -1.f + (float)(bx * 32)      * (2.f / 511.f);
        const float x1 = -1.f + (float)(bx * 32 + 31) * (2.f / 511.f);
        const float y0 = -1.f + (float)(by * 32)      * (2.f / 511.f);
        const float y1 = -1.f + (float)(by * 32 + 31) * (2.f / 511.f);
        float u00 = fmaf(x0, ca, fmaf(y0, sa, 255.5f));
        float u01 = fmaf(x1, ca, fmaf(y0, sa, 255.5f));
        float u10 = fmaf(x0, ca, fmaf(y1, sa, 255.5f));
        float u11 = fmaf(x1, ca, fmaf(y1, sa, 255.5f));
        float umin = fminf(fminf(u00, u01), fminf(u10, u11));
        int d0 = (int)floorf(umin);                    // 33-entry window
        d0 = max(0, min(NDET - 34, d0));
        ws[WS_CBT + tid * 180 + a] = 255.5f - (float)d0;
    }
    __syncthreads();

    const int b  = lane & 7;
    const int t  = lane >> 3;
    const int n0 = half_ * 256 + wv * 64 + t * 8;
    const int q  = n0 >> 2;
    const float* xrow = xs + b * 516;

    float acc[8] = {0, 0, 0, 0, 0, 0, 0, 0};
    float win[12];
    {
        int s2 = (-q - 2) & 127;
        int s1 = (-q - 1) & 127;
        float4 h2 = *(const float4*)(hrs + hswz(s2) * 4);
        float4 h1 = *(const float4*)(hrs + hswz(s1) * 4);
        win[0] = h2.x; win[1] = h2.y; win[2]  = h2.z; win[3]  = h2.w;
        win[4] = h1.x; win[5] = h1.y; win[6]  = h1.z; win[7]  = h1.w;
    }
    #pragma unroll 2
    for (int c = 0; c < 128; ++c) {
        int s = (c - q) & 127;
        float4 hc = *(const float4*)(hrs + hswz(s) * 4);
        win[8] = hc.x; win[9] = hc.y; win[10] = hc.z; win[11] = hc.w;
        float4 xv = *(const float4*)(xrow + c * 4);
        float xa[4] = {xv.x, xv.y, xv.z, xv.w};
        #pragma unroll
        for (int k = 0; k < 8; ++k)
            #pragma unroll
            for (int j = 0; j < 4; ++j)
                acc[k] = fmaf(xa[j], win[8 + j - k], acc[k]);
        #pragma unroll
        for (int i2 = 0; i2 < 8; ++i2) win[i2] = win[i2 + 4];
    }
    __half* fgh = (__half*)(ws + WS_FGH);
    #pragma unroll
    for (int k = 0; k < 8; ++k)
        fgh[(a * NDET + n0 + k) * NB + b] = __float2half(acc[k]);
}

// ---------------- kernel 2: backprojection (pre-paired LDS, 3 chunks dbuf) ----------------
// Block = 32x32 px tile, 1024 thr. 3 chunks of 60 angles; per angle 33 paired
// entries: regionA[j]=(f[j].b0,f[j+1].b0,..,b3) 16B, regionB = b4..b7.
// Pairing perms done ONCE at staging (reg-staged), not per (pixel,angle).
#define WWE  33
#define CHA  60
#define ECH  (CHA * WWE)               // 1980 entries per chunk per region

#define PERM_LO 0x05040100u
#define PERM_HI 0x07060302u

__global__ __launch_bounds__(1024, 4) void k_bp(float* ws) {
    __shared__ uint4 win4[2][2 * ECH];   // 126,720 B
    const int tid  = threadIdx.x;
    const int wv   = tid >> 6, lane = tid & 63;
    const int tile = blockIdx.x;
    const int bx   = tile & 15, by = tile >> 4;
    const int iy   = by * 32 + (wv >> 2) * 8 + (lane >> 3);
    const int ix   = bx * 32 + (wv & 3) * 8 + (lane & 7);
    const float xf = -1.0f + (float)ix * (2.0f / 511.0f);
    const float yf = -1.0f + (float)iy * (2.0f / 511.0f);

    const __half* __restrict__ fgh  = (const __half*)(ws + WS_FGH);
    const float*  __restrict__ cbt  = ws + WS_CBT + tile * 180;
    const float*  __restrict__ casa = ws + WS_CASA;

    const int e0 = tid, e1 = tid + 1024;        // e0 < 1980 always; e1 maybe
    uint4 sA0, sB0, sA1, sB1;                   // staged rows (det d, det d+1)

    auto sload = [&](int ch) {
        {
            int a = e0 / 33, j = e0 - a * 33, ag = ch * CHA + a;
            int d0 = (int)(255.5f - cbt[ag]);
            const uint4* s = (const uint4*)(fgh + (ag * NDET + d0 + j) * NB);
            sA0 = s[0]; sB0 = s[1];
        }
        if (e1 < ECH) {
            int a = e1 / 33, j = e1 - a * 33, ag = ch * CHA + a;
            int d0 = (int)(255.5f - cbt[ag]);
            const uint4* s = (const uint4*)(fgh + (ag * NDET + d0 + j) * NB);
            sA1 = s[0]; sB1 = s[1];
        }
    };
    auto swrite = [&](int buf) {
        uint4 ra, rb;
        ra.x = __builtin_amdgcn_perm(sB0.x, sA0.x, PERM_LO);
        ra.y = __builtin_amdgcn_perm(sB0.x, sA0.x, PERM_HI);
        ra.z = __builtin_amdgcn_perm(sB0.y, sA0.y, PERM_LO);
        ra.w = __builtin_amdgcn_perm(sB0.y, sA0.y, PERM_HI);
        rb.x = __builtin_amdgcn_perm(sB0.z, sA0.z, PERM_LO);
        rb.y = __builtin_amdgcn_perm(sB0.z, sA0.z, PERM_HI);
        rb.z = __builtin_amdgcn_perm(sB0.w, sA0.w, PERM_LO);
        rb.w = __builtin_amdgcn_perm(sB0.w, sA0.w, PERM_HI);
        win4[buf][e0] = ra; win4[buf][ECH + e0] = rb;
        if (e1 < ECH) {
            uint4 rc, rd;
            rc.x = __builtin_amdgcn_perm(sB1.x, sA1.x, PERM_LO);
            rc.y = __builtin_amdgcn_perm(sB1.x, sA1.x, PERM_HI);
            rc.z = __builtin_amdgcn_perm(sB1.y, sA1.y, PERM_LO);
            rc.w = __builtin_amdgcn_perm(sB1.y, sA1.y, PERM_HI);
            rd.x = __builtin_amdgcn_perm(sB1.z, sA1.z, PERM_LO);
            rd.y = __builtin_amdgcn_perm(sB1.z, sA1.z, PERM_HI);
            rd.z = __builtin_amdgcn_perm(sB1.w, sA1.w, PERM_LO);
            rd.w = __builtin_amdgcn_perm(sB1.w, sA1.w, PERM_HI);
            win4[buf][e1] = rc; win4[buf][ECH + e1] = rd;
        }
    };

    float acc[8] = {0, 0, 0, 0, 0, 0, 0, 0};
    auto comp = [&](int buf, int ch) {
        const uint4* base = &win4[buf][0];
        #pragma unroll 4
        for (int al = 0; al < CHA; ++al) {
            const int ag = ch * CHA + al;
            const float2 cs = *(const float2*)(casa + 2 * ag);   // uniform
            const float  cb = cbt[ag];                           // uniform
            float v = fmaf(xf, cs.x, fmaf(yf, cs.y, cb));
            v = __builtin_amdgcn_fmed3f(v, 0.0f, 32.99996948f);
            float fj = floorf(v);
            float w  = v - fj;
            int  j0  = (int)fj;
            const uint4* p = base + al * WWE + j0;
            uint4 dA = p[0];          // (A,B) pairs batches 0..3
            uint4 dB = p[ECH];        // (A,B) pairs batches 4..7
            h2_t wp = __builtin_bit_cast(h2_t, __builtin_amdgcn_cvt_pkrtz(1.0f - w, w));
            acc[0] = __builtin_amdgcn_fdot2(__builtin_bit_cast(h2_t, dA.x), wp, acc[0], false);
            acc[1] = __builtin_amdgcn_fdot2(__builtin_bit_cast(h2_t, dA.y), wp, acc[1], false);
            acc[2] = __builtin_amdgcn_fdot2(__builtin_bit_cast(h2_t, dA.z), wp, acc[2], false);
            acc[3] = __builtin_amdgcn_fdot2(__builtin_bit_cast(h2_t, dA.w), wp, acc[3], false);
            acc[4] = __builtin_amdgcn_fdot2(__builtin_bit_cast(h2_t, dB.x), wp, acc[4], false);
            acc[5] = __builtin_amdgcn_fdot2(__builtin_bit_cast(h2_t, dB.y), wp, acc[5], false);
            acc[6] = __builtin_amdgcn_fdot2(__builtin_bit_cast(h2_t, dB.z), wp, acc[6], false);
            acc[7] = __builtin_amdgcn_fdot2(__builtin_bit_cast(h2_t, dB.w), wp, acc[7], false);
        }
    };

    // chunk pipeline: ch0->buf0, ch1->buf1, ch2->buf0 (T14 async-stage)
    sload(0); swrite(0); __syncthreads();
    sload(1); comp(0, 0); swrite(1); __syncthreads();
    sload(2); comp(1, 1); swrite(0); __syncthreads();
    comp(0, 2);

    const float scale = (float)((2.0 / 512.0) * M_PI / 180.0);
    float* bp = ws + WS_BP;
    #pragma unroll
    for (int b = 0; b < 8; ++b)
        bp[b * (NIMG * NIMG) + iy * NIMG + ix] = acc[b] * scale;
}

// ---------------- kernel 3: 3x3 gaussian blur + clip ----------------
__global__ __launch_bounds__(256) void k_blur(const float* __restrict__ ws, float* __restrict__ out) {
    const int gid = blockIdx.x * 256 + threadIdx.x;
    const int b  = gid >> 18;
    const int r  = (gid >> 9) & 511;
    const int cx = gid & 511;
    const float KA = 0.10650697891920077f;   // e^-2 / (1+2e^-2)
    const float KB = 0.78698604216159850f;   // 1 / (1+2e^-2)
    const float* img = ws + WS_BP + b * (NIMG * NIMG);
    const float* rp = img + r * 512 + cx;

    float rowm = 0.0f, row0, rowp = 0.0f;
    {
        float l  = (cx > 0)   ? rp[-1] : 0.0f;
        float rr = (cx < 511) ? rp[1]  : 0.0f;
        row0 = KA * (l + rr) + KB * rp[0];
    }
    if (r > 0) {
        const float* q = rp - 512;
        float l  = (cx > 0)   ? q[-1] : 0.0f;
        float rr = (cx < 511) ? q[1]  : 0.0f;
        rowm = KA * (l + rr) + KB * q[0];
    }
    if (r < 511) {
        const float* q = rp + 512;
        float l  = (cx > 0)   ? q[-1] : 0.0f;
        float rr = (cx < 511) ? q[1]  : 0.0f;
        rowp = KA * (l + rr) + KB * q[0];
    }
    float v = KA * (rowm + rowp) + KB * row0;
    v = fminf(fmaxf(v, -1.0f), 1.0f);
    out[gid] = v;
}

extern "C" void kernel_launch(void* const* d_in, const int* in_sizes, int n_in,
                              void* d_out, int out_size, void* d_ws, size_t ws_size,
                              hipStream_t stream) {
    const float* x = (const float*)d_in[0];
    float* out = (float*)d_out;
    float* ws  = (float*)d_ws;

    k_filter<<<NANG * 2, 256, 0, stream>>>(x, ws);
    k_bp<<<256, 1024, 0, stream>>>(ws);
    k_blur<<<(NB * NIMG * NIMG) / 256, 256, 0, stream>>>(ws, out);
}